// Round 1
// baseline (1185.224 us; speedup 1.0000x reference)
//
#include <hip/hip_runtime.h>

#define NNODES 50000
#define NEDGES 640000
#define NF 128

constexpr int STW = 132;  // padded LDS stride for W (keeps 16B align, breaks bank stride)

// ---------------- K0: h = x, zero BN stats ----------------
__global__ __launch_bounds__(256) void k_init(const float* __restrict__ x,
                                              float* __restrict__ h,
                                              float* __restrict__ stats) {
  int t = blockIdx.x * 256 + threadIdx.x;
  ((float4*)h)[t] = ((const float4*)x)[t];
  if (blockIdx.x == 0) stats[threadIdx.x] = 0.f;  // sums[128] + sumsq[128]
}

// ---------------- K1: scatter-add  h[dst] += x[src] ----------------
__global__ __launch_bounds__(256) void k_scatter(const float* __restrict__ x,
                                                 const int* __restrict__ ei,
                                                 float* __restrict__ h) {
  int tid = blockIdx.x * 256 + threadIdx.x;
  int e = tid >> 5;            // 32 lanes per edge
  int c = (tid & 31) << 2;     // 4 floats per lane
  int s = ei[e];
  int d = ei[NEDGES + e];
  float4 v = *(const float4*)(x + (size_t)s * NF + c);
  float* p = h + (size_t)d * NF + c;
  unsafeAtomicAdd(p + 0, v.x);
  unsafeAtomicAdd(p + 1, v.y);
  unsafeAtomicAdd(p + 2, v.z);
  unsafeAtomicAdd(p + 3, v.w);
}

// ---------------- GEMM: out = A(50000x128) @ W(128x128) + bias, epilogues ----------------
// MODE 0: (GEMM1) relu, write back in-place, accumulate BN sums/sumsq via atomics
// MODE 1: (GEMM2) BN affine (scale/shift per K-column) applied on A load, write d_out
template <int MODE>
__global__ __launch_bounds__(256) void k_gemm(const float* __restrict__ A,
                                              const float* __restrict__ W,
                                              const float* __restrict__ bias,
                                              const float* __restrict__ scsh,
                                              float* __restrict__ stats,
                                              float* __restrict__ out) {
  __shared__ float As[128 * 128];   // 64 KB, XOR-swizzled within row
  __shared__ float Ws[128 * STW];   // 66 KB, padded stride

  const int t = threadIdx.x;
  const int row0 = blockIdx.x * 128;

  // ---- stage W and A tile (4096 float4 each, 16 iters) ----
  const float4* W4 = (const float4*)W;
#pragma unroll
  for (int it = 0; it < 16; ++it) {
    int flat = it * 256 + t;        // float4 index 0..4095
    int rk = flat >> 5;             // 0..127
    int c4 = (flat & 31) << 2;      // 0,4,...,124
    float4 w = W4[flat];
    *(float4*)(Ws + rk * STW + c4) = w;

    int grow = row0 + rk;
    float4 a = make_float4(0.f, 0.f, 0.f, 0.f);
    if (grow < NNODES) a = *(const float4*)(A + (size_t)grow * NF + c4);
    if (MODE == 1) {
      const float4 sc = *(const float4*)(scsh + c4);
      const float4 sh = *(const float4*)(scsh + 128 + c4);
      a.x = a.x * sc.x + sh.x;
      a.y = a.y * sc.y + sh.y;
      a.z = a.z * sc.z + sh.z;
      a.w = a.w * sc.w + sh.w;
    }
    int kswz = c4 ^ (((rk >> 2) & 7) << 2);  // bank swizzle keyed on row>>2
    *(float4*)(As + rk * 128 + kswz) = a;
  }
  __syncthreads();

  // ---- compute: thread (tr,tc) owns rows {4tr+i, 64+4tr+i}, cols {4tc+j, 64+4tc+j} ----
  const int tr = t >> 4;           // 0..15
  const int tc = t & 15;           // 0..15
  const int swz = (tr & 7) << 2;
  const int r0 = 4 * tr;
  const int c0 = 4 * tc;

  float acc[8][8];
#pragma unroll
  for (int i = 0; i < 8; ++i)
#pragma unroll
    for (int j = 0; j < 8; ++j) acc[i][j] = 0.f;

#pragma unroll 4
  for (int k = 0; k < 128; ++k) {
    int ks = k ^ swz;
    float a[8];
#pragma unroll
    for (int i = 0; i < 8; ++i) {
      int r = r0 + (i & 3) + ((i >> 2) << 6);
      a[i] = As[r * 128 + ks];
    }
    float w[8];
    const float4 wlo = *(const float4*)(Ws + k * STW + c0);
    const float4 whi = *(const float4*)(Ws + k * STW + c0 + 64);
    w[0] = wlo.x; w[1] = wlo.y; w[2] = wlo.z; w[3] = wlo.w;
    w[4] = whi.x; w[5] = whi.y; w[6] = whi.z; w[7] = whi.w;
#pragma unroll
    for (int i = 0; i < 8; ++i)
#pragma unroll
      for (int j = 0; j < 8; ++j) acc[i][j] = fmaf(a[i], w[j], acc[i][j]);
  }

  // ---- epilogue ----
  float bl[8];
#pragma unroll
  for (int j = 0; j < 8; ++j) bl[j] = bias[c0 + (j & 3) + ((j >> 2) << 6)];

  if (MODE == 0) {
    float csum[8], csq[8];
#pragma unroll
    for (int j = 0; j < 8; ++j) { csum[j] = 0.f; csq[j] = 0.f; }
#pragma unroll
    for (int i = 0; i < 8; ++i) {
      int rl = r0 + (i & 3) + ((i >> 2) << 6);
      int r = row0 + rl;
      if (r < NNODES) {
        float v[8];
#pragma unroll
        for (int j = 0; j < 8; ++j) v[j] = fmaxf(acc[i][j] + bl[j], 0.f);
        *(float4*)(out + (size_t)r * NF + c0) = make_float4(v[0], v[1], v[2], v[3]);
        *(float4*)(out + (size_t)r * NF + c0 + 64) = make_float4(v[4], v[5], v[6], v[7]);
#pragma unroll
        for (int j = 0; j < 8; ++j) { csum[j] += v[j]; csq[j] += v[j] * v[j]; }
      }
    }
    // block-level column reduction via LDS (reuse Ws), then one atomic per column
    __syncthreads();
    float* red = Ws;  // [16][128]
#pragma unroll
    for (int j = 0; j < 8; ++j) red[tr * 128 + c0 + (j & 3) + ((j >> 2) << 6)] = csum[j];
    __syncthreads();
    if (t < 128) {
      float s = 0.f;
      for (int g = 0; g < 16; ++g) s += red[g * 128 + t];
      unsafeAtomicAdd(stats + t, s);
    }
    __syncthreads();
#pragma unroll
    for (int j = 0; j < 8; ++j) red[tr * 128 + c0 + (j & 3) + ((j >> 2) << 6)] = csq[j];
    __syncthreads();
    if (t < 128) {
      float s = 0.f;
      for (int g = 0; g < 16; ++g) s += red[g * 128 + t];
      unsafeAtomicAdd(stats + 128 + t, s);
    }
  } else {
#pragma unroll
    for (int i = 0; i < 8; ++i) {
      int rl = r0 + (i & 3) + ((i >> 2) << 6);
      int r = row0 + rl;
      if (r < NNODES) {
        float v[8];
#pragma unroll
        for (int j = 0; j < 8; ++j) v[j] = acc[i][j] + bl[j];
        *(float4*)(out + (size_t)r * NF + c0) = make_float4(v[0], v[1], v[2], v[3]);
        *(float4*)(out + (size_t)r * NF + c0 + 64) = make_float4(v[4], v[5], v[6], v[7]);
      }
    }
  }
}

// ---------------- K3: BN scale/shift finalize ----------------
__global__ __launch_bounds__(128) void k_bnfin(const float* __restrict__ stats,
                                               const float* __restrict__ gamma,
                                               const float* __restrict__ beta,
                                               float* __restrict__ scsh) {
  int c = threadIdx.x;
  const float inv = 1.0f / (float)NNODES;
  float mean = stats[c] * inv;
  float var = stats[128 + c] * inv - mean * mean;
  var = fmaxf(var, 0.f);
  float sc = gamma[c] * rsqrtf(var + 1e-5f);
  scsh[c] = sc;
  scsh[128 + c] = beta[c] - mean * sc;
}

extern "C" void kernel_launch(void* const* d_in, const int* in_sizes, int n_in,
                              void* d_out, int out_size, void* d_ws, size_t ws_size,
                              hipStream_t stream) {
  const float* x     = (const float*)d_in[0];
  const int*   ei    = (const int*)d_in[1];
  const float* W1    = (const float*)d_in[2];
  const float* b1    = (const float*)d_in[3];
  const float* gamma = (const float*)d_in[4];
  const float* beta  = (const float*)d_in[5];
  const float* W2    = (const float*)d_in[6];
  const float* b2    = (const float*)d_in[7];
  float* out = (float*)d_out;

  float* h     = (float*)d_ws;                  // 50000*128 floats
  float* stats = h + (size_t)NNODES * NF;       // sums[128] sumsq[128] scale[128] shift[128]

  k_init<<<(NNODES * NF / 4) / 256, 256, 0, stream>>>(x, h, stats);
  k_scatter<<<NEDGES * 32 / 256, 256, 0, stream>>>(x, ei, h);
  k_gemm<0><<<(NNODES + 127) / 128, 256, 0, stream>>>(h, W1, b1, nullptr, stats, h);
  k_bnfin<<<1, 128, 0, stream>>>(stats, gamma, beta, stats + 256);
  k_gemm<1><<<(NNODES + 127) / 128, 256, 0, stream>>>(h, W2, b2, stats + 256, nullptr, out);
}

// Round 2
// 221.751 us; speedup vs baseline: 5.3449x; 5.3449x over previous
//
#include <hip/hip_runtime.h>

#define NNODES 50000
#define NEDGES 640000
#define NF 128
#define NB 196            // scan blocks: 196*256 = 50176 >= NNODES

constexpr int STW = 132;  // padded LDS stride for W

// ---------------- K: zero degree counters + BN stats ----------------
__global__ __launch_bounds__(256) void k_zero(int* __restrict__ deg,
                                              float* __restrict__ stats) {
  int i = blockIdx.x * 256 + threadIdx.x;
  if (i < NB * 256) deg[i] = 0;
  if (blockIdx.x == 0) stats[threadIdx.x] = 0.f;  // sums[128]+sumsq[128]
}

// ---------------- K: histogram of dst ----------------
__global__ __launch_bounds__(256) void k_hist(const int* __restrict__ ei,
                                              int* __restrict__ deg) {
  int e = blockIdx.x * 256 + threadIdx.x;
  atomicAdd(&deg[ei[NEDGES + e]], 1);
}

// ---------------- K: scan stage 1 — per-block sums ----------------
__global__ __launch_bounds__(256) void k_scan1(const int* __restrict__ deg,
                                               int* __restrict__ bsum) {
  __shared__ int s[256];
  int t = threadIdx.x;
  s[t] = deg[blockIdx.x * 256 + t];
  __syncthreads();
  for (int d = 128; d > 0; d >>= 1) {
    if (t < d) s[t] += s[t + d];
    __syncthreads();
  }
  if (t == 0) bsum[blockIdx.x] = s[0];
}

// ---------------- K: scan stage 2 — exclusive scan of block sums ----------------
__global__ __launch_bounds__(256) void k_scan2(const int* __restrict__ bsum,
                                               int* __restrict__ boff) {
  __shared__ int s[256];
  int t = threadIdx.x;
  int v = (t < NB) ? bsum[t] : 0;
  s[t] = v;
  __syncthreads();
  for (int d = 1; d < 256; d <<= 1) {
    int u = (t >= d) ? s[t - d] : 0;
    __syncthreads();
    s[t] += u;
    __syncthreads();
  }
  if (t < NB) boff[t] = s[t] - v;  // exclusive
}

// ---------------- K: scan stage 3 — full exclusive scan, init offsets+cursors ----------------
__global__ __launch_bounds__(256) void k_scan3(const int* __restrict__ deg,
                                               const int* __restrict__ boff,
                                               int* __restrict__ off,
                                               int* __restrict__ cursor) {
  __shared__ int s[256];
  int t = threadIdx.x;
  int i = blockIdx.x * 256 + t;
  int v = deg[i];
  s[t] = v;
  __syncthreads();
  for (int d = 1; d < 256; d <<= 1) {
    int u = (t >= d) ? s[t - d] : 0;
    __syncthreads();
    s[t] += u;
    __syncthreads();
  }
  int excl = boff[blockIdx.x] + s[t] - v;
  if (i < NNODES) {
    off[i] = excl;
    cursor[i] = excl;
  }
  if (i == 0) off[NNODES] = NEDGES;
}

// ---------------- K: reorder — slot[pos] = src, bucketed by dst ----------------
__global__ __launch_bounds__(256) void k_reorder(const int* __restrict__ ei,
                                                 int* __restrict__ cursor,
                                                 int* __restrict__ slot) {
  int e = blockIdx.x * 256 + threadIdx.x;
  int d = ei[NEDGES + e];
  int pos = atomicAdd(&cursor[d], 1);
  slot[pos] = ei[e];
}

// ---------------- K: gather-sum  h[i] = x[i] + sum_{s in adj(i)} x[s] ----------------
__global__ __launch_bounds__(256) void k_gather(const float* __restrict__ x,
                                                const int* __restrict__ off,
                                                const int* __restrict__ slot,
                                                float* __restrict__ h) {
  int t = threadIdx.x;
  int node = blockIdx.x * 8 + (t >> 5);  // half-warp per node
  int c = (t & 31) << 2;                 // 4 floats per lane
  if (node >= NNODES) return;
  int beg = off[node], end = off[node + 1];
  float4 a0 = *(const float4*)(x + (size_t)node * NF + c);
  float4 a1 = make_float4(0.f, 0.f, 0.f, 0.f);
  int j = beg;
  for (; j + 1 < end; j += 2) {
    int s0 = slot[j], s1 = slot[j + 1];
    float4 v0 = *(const float4*)(x + (size_t)s0 * NF + c);
    float4 v1 = *(const float4*)(x + (size_t)s1 * NF + c);
    a0.x += v0.x; a0.y += v0.y; a0.z += v0.z; a0.w += v0.w;
    a1.x += v1.x; a1.y += v1.y; a1.z += v1.z; a1.w += v1.w;
  }
  if (j < end) {
    int s0 = slot[j];
    float4 v0 = *(const float4*)(x + (size_t)s0 * NF + c);
    a0.x += v0.x; a0.y += v0.y; a0.z += v0.z; a0.w += v0.w;
  }
  a0.x += a1.x; a0.y += a1.y; a0.z += a1.z; a0.w += a1.w;
  *(float4*)(h + (size_t)node * NF + c) = a0;
}

// ---------------- GEMM: out = A(50000x128) @ W(128x128) + bias, epilogues ----------------
template <int MODE>
__global__ __launch_bounds__(256) void k_gemm(const float* __restrict__ A,
                                              const float* __restrict__ W,
                                              const float* __restrict__ bias,
                                              const float* __restrict__ scsh,
                                              float* __restrict__ stats,
                                              float* __restrict__ out) {
  __shared__ float As[128 * 128];
  __shared__ float Ws[128 * STW];

  const int t = threadIdx.x;
  const int row0 = blockIdx.x * 128;

  const float4* W4 = (const float4*)W;
#pragma unroll
  for (int it = 0; it < 16; ++it) {
    int flat = it * 256 + t;
    int rk = flat >> 5;
    int c4 = (flat & 31) << 2;
    float4 w = W4[flat];
    *(float4*)(Ws + rk * STW + c4) = w;

    int grow = row0 + rk;
    float4 a = make_float4(0.f, 0.f, 0.f, 0.f);
    if (grow < NNODES) a = *(const float4*)(A + (size_t)grow * NF + c4);
    if (MODE == 1) {
      const float4 sc = *(const float4*)(scsh + c4);
      const float4 sh = *(const float4*)(scsh + 128 + c4);
      a.x = a.x * sc.x + sh.x;
      a.y = a.y * sc.y + sh.y;
      a.z = a.z * sc.z + sh.z;
      a.w = a.w * sc.w + sh.w;
    }
    int kswz = c4 ^ (((rk >> 2) & 7) << 2);
    *(float4*)(As + rk * 128 + kswz) = a;
  }
  __syncthreads();

  const int tr = t >> 4;
  const int tc = t & 15;
  const int swz = (tr & 7) << 2;
  const int r0 = 4 * tr;
  const int c0 = 4 * tc;

  float acc[8][8];
#pragma unroll
  for (int i = 0; i < 8; ++i)
#pragma unroll
    for (int j = 0; j < 8; ++j) acc[i][j] = 0.f;

#pragma unroll 4
  for (int k = 0; k < 128; ++k) {
    int ks = k ^ swz;
    float a[8];
#pragma unroll
    for (int i = 0; i < 8; ++i) {
      int r = r0 + (i & 3) + ((i >> 2) << 6);
      a[i] = As[r * 128 + ks];
    }
    float w[8];
    const float4 wlo = *(const float4*)(Ws + k * STW + c0);
    const float4 whi = *(const float4*)(Ws + k * STW + c0 + 64);
    w[0] = wlo.x; w[1] = wlo.y; w[2] = wlo.z; w[3] = wlo.w;
    w[4] = whi.x; w[5] = whi.y; w[6] = whi.z; w[7] = whi.w;
#pragma unroll
    for (int i = 0; i < 8; ++i)
#pragma unroll
      for (int j = 0; j < 8; ++j) acc[i][j] = fmaf(a[i], w[j], acc[i][j]);
  }

  float bl[8];
#pragma unroll
  for (int j = 0; j < 8; ++j) bl[j] = bias[c0 + (j & 3) + ((j >> 2) << 6)];

  if (MODE == 0) {
    float csum[8], csq[8];
#pragma unroll
    for (int j = 0; j < 8; ++j) { csum[j] = 0.f; csq[j] = 0.f; }
#pragma unroll
    for (int i = 0; i < 8; ++i) {
      int rl = r0 + (i & 3) + ((i >> 2) << 6);
      int r = row0 + rl;
      if (r < NNODES) {
        float v[8];
#pragma unroll
        for (int j = 0; j < 8; ++j) v[j] = fmaxf(acc[i][j] + bl[j], 0.f);
        *(float4*)(out + (size_t)r * NF + c0) = make_float4(v[0], v[1], v[2], v[3]);
        *(float4*)(out + (size_t)r * NF + c0 + 64) = make_float4(v[4], v[5], v[6], v[7]);
#pragma unroll
        for (int j = 0; j < 8; ++j) { csum[j] += v[j]; csq[j] += v[j] * v[j]; }
      }
    }
    __syncthreads();
    float* red = Ws;  // reuse as [16][128]
#pragma unroll
    for (int j = 0; j < 8; ++j) red[tr * 128 + c0 + (j & 3) + ((j >> 2) << 6)] = csum[j];
    __syncthreads();
    if (t < 128) {
      float s = 0.f;
      for (int g = 0; g < 16; ++g) s += red[g * 128 + t];
      unsafeAtomicAdd(stats + t, s);
    }
    __syncthreads();
#pragma unroll
    for (int j = 0; j < 8; ++j) red[tr * 128 + c0 + (j & 3) + ((j >> 2) << 6)] = csq[j];
    __syncthreads();
    if (t < 128) {
      float s = 0.f;
      for (int g = 0; g < 16; ++g) s += red[g * 128 + t];
      unsafeAtomicAdd(stats + 128 + t, s);
    }
  } else {
#pragma unroll
    for (int i = 0; i < 8; ++i) {
      int rl = r0 + (i & 3) + ((i >> 2) << 6);
      int r = row0 + rl;
      if (r < NNODES) {
        float v[8];
#pragma unroll
        for (int j = 0; j < 8; ++j) v[j] = acc[i][j] + bl[j];
        *(float4*)(out + (size_t)r * NF + c0) = make_float4(v[0], v[1], v[2], v[3]);
        *(float4*)(out + (size_t)r * NF + c0 + 64) = make_float4(v[4], v[5], v[6], v[7]);
      }
    }
  }
}

// ---------------- K: BN scale/shift finalize ----------------
__global__ __launch_bounds__(128) void k_bnfin(const float* __restrict__ stats,
                                               const float* __restrict__ gamma,
                                               const float* __restrict__ beta,
                                               float* __restrict__ scsh) {
  int c = threadIdx.x;
  const float inv = 1.0f / (float)NNODES;
  float mean = stats[c] * inv;
  float var = stats[128 + c] * inv - mean * mean;
  var = fmaxf(var, 0.f);
  float sc = gamma[c] * rsqrtf(var + 1e-5f);
  scsh[c] = sc;
  scsh[128 + c] = beta[c] - mean * sc;
}

extern "C" void kernel_launch(void* const* d_in, const int* in_sizes, int n_in,
                              void* d_out, int out_size, void* d_ws, size_t ws_size,
                              hipStream_t stream) {
  const float* x     = (const float*)d_in[0];
  const int*   ei    = (const int*)d_in[1];
  const float* W1    = (const float*)d_in[2];
  const float* b1    = (const float*)d_in[3];
  const float* gamma = (const float*)d_in[4];
  const float* beta  = (const float*)d_in[5];
  const float* W2    = (const float*)d_in[6];
  const float* b2    = (const float*)d_in[7];
  float* out = (float*)d_out;

  // h lives in d_out (fully overwritten in-place by the GEMMs, block-local rows)
  float* h = (float*)d_out;

  // workspace: stats + CSR arrays (~3.2 MB)
  float* stats  = (float*)d_ws;            // sums[128] sumsq[128] scale[128] shift[128]
  int*   deg    = (int*)(stats + 512);     // [NB*256]
  int*   off    = deg + NB * 256;          // [NNODES+1] (+pad)
  int*   cursor = off + NNODES + 4;        // [NNODES]
  int*   bsum   = cursor + NNODES;         // [256]
  int*   boff   = bsum + 256;              // [256]
  int*   slot   = boff + 256;              // [NEDGES]

  k_zero   <<<NB, 256, 0, stream>>>(deg, stats);
  k_hist   <<<NEDGES / 256, 256, 0, stream>>>(ei, deg);
  k_scan1  <<<NB, 256, 0, stream>>>(deg, bsum);
  k_scan2  <<<1, 256, 0, stream>>>(bsum, boff);
  k_scan3  <<<NB, 256, 0, stream>>>(deg, boff, off, cursor);
  k_reorder<<<NEDGES / 256, 256, 0, stream>>>(ei, cursor, slot);
  k_gather <<<(NNODES + 7) / 8, 256, 0, stream>>>(x, off, slot, h);
  k_gemm<0><<<(NNODES + 127) / 128, 256, 0, stream>>>(h, W1, b1, nullptr, stats, h);
  k_bnfin  <<<1, 128, 0, stream>>>(stats, gamma, beta, stats + 256);
  k_gemm<1><<<(NNODES + 127) / 128, 256, 0, stream>>>(h, W2, b2, stats + 256, nullptr, out);
}

// Round 3
// 179.224 us; speedup vs baseline: 6.6131x; 1.2373x over previous
//
#include <hip/hip_runtime.h>

#define NNODES 50000
#define NEDGES 640000
#define NF 128
#define NB 196            // scan blocks: 196*256 = 50176 >= NNODES

typedef __attribute__((ext_vector_type(8))) short bf16x8;
typedef __attribute__((ext_vector_type(4))) float f32x4;

__device__ inline unsigned short f2bf(float f) {
  unsigned u = __float_as_uint(f);
  u += 0x7fffu + ((u >> 16) & 1u);   // round-to-nearest-even
  return (unsigned short)(u >> 16);
}
__device__ inline float bf2f(unsigned short s) {
  return __uint_as_float((unsigned)s << 16);
}

// ---------------- K: zero degree counters + BN stats ----------------
__global__ __launch_bounds__(256) void k_zero(int* __restrict__ deg,
                                              float* __restrict__ stats) {
  int i = blockIdx.x * 256 + threadIdx.x;
  if (i < NB * 256) deg[i] = 0;
  if (blockIdx.x == 0) stats[threadIdx.x] = 0.f;
}

// ---------------- K: W -> fragment-ordered bf16 hi/lo (both W1, W2) ----------------
// frag index f = (((ks*8+cf)*64)+lane)*8 + j ;  k = ks*32+(lane>>4)*8+j ; n = cf*16+(lane&15)
__global__ __launch_bounds__(256) void k_wprep(const float* __restrict__ W1,
                                               const float* __restrict__ W2,
                                               unsigned short* __restrict__ wp) {
  int i = blockIdx.x * 256 + threadIdx.x;   // 0..32767
  int which = i >> 14;
  int f = i & 16383;
  int j = f & 7, lane = (f >> 3) & 63, cf = (f >> 9) & 7, ks = f >> 12;
  int k = ks * 32 + ((lane >> 4) << 3) + j;
  int n = cf * 16 + (lane & 15);
  float w = (which ? W2 : W1)[k * NF + n];
  unsigned short hi = f2bf(w);
  unsigned short lo = f2bf(w - bf2f(hi));
  unsigned short* dst = wp + which * 32768;
  dst[f] = hi;
  dst[16384 + f] = lo;
}

// ---------------- K: histogram of dst ----------------
__global__ __launch_bounds__(256) void k_hist(const int* __restrict__ ei,
                                              int* __restrict__ deg) {
  int e = blockIdx.x * 256 + threadIdx.x;
  atomicAdd(&deg[ei[NEDGES + e]], 1);
}

// ---------------- scan stages ----------------
__global__ __launch_bounds__(256) void k_scan1(const int* __restrict__ deg,
                                               int* __restrict__ bsum) {
  __shared__ int s[256];
  int t = threadIdx.x;
  s[t] = deg[blockIdx.x * 256 + t];
  __syncthreads();
  for (int d = 128; d > 0; d >>= 1) {
    if (t < d) s[t] += s[t + d];
    __syncthreads();
  }
  if (t == 0) bsum[blockIdx.x] = s[0];
}

__global__ __launch_bounds__(256) void k_scan2(const int* __restrict__ bsum,
                                               int* __restrict__ boff) {
  __shared__ int s[256];
  int t = threadIdx.x;
  int v = (t < NB) ? bsum[t] : 0;
  s[t] = v;
  __syncthreads();
  for (int d = 1; d < 256; d <<= 1) {
    int u = (t >= d) ? s[t - d] : 0;
    __syncthreads();
    s[t] += u;
    __syncthreads();
  }
  if (t < NB) boff[t] = s[t] - v;
}

__global__ __launch_bounds__(256) void k_scan3(const int* __restrict__ deg,
                                               const int* __restrict__ boff,
                                               int* __restrict__ off,
                                               int* __restrict__ cursor) {
  __shared__ int s[256];
  int t = threadIdx.x;
  int i = blockIdx.x * 256 + t;
  int v = deg[i];
  s[t] = v;
  __syncthreads();
  for (int d = 1; d < 256; d <<= 1) {
    int u = (t >= d) ? s[t - d] : 0;
    __syncthreads();
    s[t] += u;
    __syncthreads();
  }
  int excl = boff[blockIdx.x] + s[t] - v;
  if (i < NNODES) {
    off[i] = excl;
    cursor[i] = excl;
  }
  if (i == 0) off[NNODES] = NEDGES;
}

// ---------------- K: reorder — slot[pos] = src, bucketed by dst ----------------
__global__ __launch_bounds__(256) void k_reorder(const int* __restrict__ ei,
                                                 int* __restrict__ cursor,
                                                 int* __restrict__ slot) {
  int e = blockIdx.x * 256 + threadIdx.x;
  int d = ei[NEDGES + e];
  int pos = atomicAdd(&cursor[d], 1);
  slot[pos] = ei[e];
}

// ---------------- K: gather-sum, one wave per node ----------------
__global__ __launch_bounds__(256) void k_gather(const float* __restrict__ x,
                                                const int* __restrict__ off,
                                                const int* __restrict__ slot,
                                                float* __restrict__ h) {
  int t = threadIdx.x;
  int l = t & 63;
  int node = blockIdx.x * 4 + (t >> 6);
  if (node >= NNODES) return;
  int c = (l & 31) << 2;
  int half = l >> 5;
  int beg = off[node], end = off[node + 1];
  float4 a = make_float4(0.f, 0.f, 0.f, 0.f);
  float4 b = make_float4(0.f, 0.f, 0.f, 0.f);
  int j = beg + half;
  for (; j + 2 < end; j += 4) {
    int s0 = slot[j], s1 = slot[j + 2];
    float4 v0 = *(const float4*)(x + (size_t)s0 * NF + c);
    float4 v1 = *(const float4*)(x + (size_t)s1 * NF + c);
    a.x += v0.x; a.y += v0.y; a.z += v0.z; a.w += v0.w;
    b.x += v1.x; b.y += v1.y; b.z += v1.z; b.w += v1.w;
  }
  if (j < end) {
    int s0 = slot[j];
    float4 v0 = *(const float4*)(x + (size_t)s0 * NF + c);
    a.x += v0.x; a.y += v0.y; a.z += v0.z; a.w += v0.w;
  }
  a.x += b.x; a.y += b.y; a.z += b.z; a.w += b.w;
  a.x += __shfl_xor(a.x, 32);
  a.y += __shfl_xor(a.y, 32);
  a.z += __shfl_xor(a.z, 32);
  a.w += __shfl_xor(a.w, 32);
  if (half == 0) {
    const float4 sv = *(const float4*)(x + (size_t)node * NF + c);
    a.x += sv.x; a.y += sv.y; a.z += sv.z; a.w += sv.w;
    *(float4*)(h + (size_t)node * NF + c) = a;
  }
}

// ---------------- MFMA GEMM: out = A(50000x128) @ W(128x128) + bias ----------------
// bf16x3 fp32-emulation. A: global->reg fragments. W: frag-ordered global buffer -> LDS.
// MODE 0: relu, in-place, BN sum/sumsq.  MODE 1: BN affine on A, +b2, write out.
template <int MODE>
__global__ __launch_bounds__(256, 2) void k_gemm(const float* __restrict__ A,
                                                 const unsigned short* __restrict__ wprep,
                                                 const float* __restrict__ bias,
                                                 const float* __restrict__ scsh,
                                                 float* __restrict__ stats,
                                                 float* __restrict__ out) {
  __shared__ unsigned short wl[32768];   // 64 KB: hi[16384] then lo[16384]
  __shared__ float red[2][4][128];       // 4 KB: BN cross-wave reduce

  const int t = threadIdx.x;
  const int wv = t >> 6;
  const int l = t & 63;
  const int wrow0 = blockIdx.x * 64 + wv * 16;

  // ---- A fragments: row = wrow0 + (l&15); k = ks*32 + (l>>4)*8 + j  (8 floats = 2 float4)
  const int arow = wrow0 + (l & 15);
  const bool okA = arow < NNODES;
  float4 areg[8];
#pragma unroll
  for (int ks = 0; ks < 4; ++ks) {
    if (okA) {
      const float* p = A + (size_t)arow * NF + ks * 32 + ((l >> 4) << 3);
      areg[2 * ks]     = *(const float4*)(p);
      areg[2 * ks + 1] = *(const float4*)(p + 4);
    } else {
      areg[2 * ks] = areg[2 * ks + 1] = make_float4(0.f, 0.f, 0.f, 0.f);
    }
  }

  // ---- stage frag-ordered W (64 KB) ----
  const float4* src = (const float4*)wprep;
#pragma unroll
  for (int it = 0; it < 16; ++it) {
    ((float4*)wl)[it * 256 + t] = src[it * 256 + t];
  }
  __syncthreads();

  // ---- compute ----
  f32x4 acc[8];
#pragma unroll
  for (int cf = 0; cf < 8; ++cf) acc[cf] = (f32x4){0.f, 0.f, 0.f, 0.f};

#pragma unroll
  for (int ks = 0; ks < 4; ++ks) {
    float av[8];
    float4 a0 = areg[2 * ks], a1 = areg[2 * ks + 1];
    av[0] = a0.x; av[1] = a0.y; av[2] = a0.z; av[3] = a0.w;
    av[4] = a1.x; av[5] = a1.y; av[6] = a1.z; av[7] = a1.w;
    if (MODE == 1) {
      const float* scp = scsh + ks * 32 + ((l >> 4) << 3);
      const float4 sc0 = *(const float4*)(scp);
      const float4 sc1 = *(const float4*)(scp + 4);
      const float4 sh0 = *(const float4*)(scp + 128);
      const float4 sh1 = *(const float4*)(scp + 132);
      av[0] = fmaf(av[0], sc0.x, sh0.x); av[1] = fmaf(av[1], sc0.y, sh0.y);
      av[2] = fmaf(av[2], sc0.z, sh0.z); av[3] = fmaf(av[3], sc0.w, sh0.w);
      av[4] = fmaf(av[4], sc1.x, sh1.x); av[5] = fmaf(av[5], sc1.y, sh1.y);
      av[6] = fmaf(av[6], sc1.z, sh1.z); av[7] = fmaf(av[7], sc1.w, sh1.w);
    }
    bf16x8 ah, al;
#pragma unroll
    for (int j = 0; j < 8; ++j) {
      unsigned short hi = f2bf(av[j]);
      ah[j] = (short)hi;
      al[j] = (short)f2bf(av[j] - bf2f(hi));
    }
#pragma unroll
    for (int cf = 0; cf < 8; ++cf) {
      const int fo = (((ks * 8 + cf) << 6) + l) << 3;   // ushort offset
      bf16x8 bh = *(const bf16x8*)(wl + fo);
      bf16x8 bl2 = *(const bf16x8*)(wl + 16384 + fo);
      acc[cf] = __builtin_amdgcn_mfma_f32_16x16x32_bf16(ah, bh, acc[cf], 0, 0, 0);
      acc[cf] = __builtin_amdgcn_mfma_f32_16x16x32_bf16(al, bh, acc[cf], 0, 0, 0);
      acc[cf] = __builtin_amdgcn_mfma_f32_16x16x32_bf16(ah, bl2, acc[cf], 0, 0, 0);
    }
  }

  // ---- epilogue: D layout col = cf*16+(l&15), row = wrow0 + (l>>4)*4 + r ----
  const int col16 = l & 15;
  const int rg = l >> 4;
  float bl_[8];
#pragma unroll
  for (int cf = 0; cf < 8; ++cf) bl_[cf] = bias[cf * 16 + col16];

  if (MODE == 0) {
    float cs[8], cq[8];
#pragma unroll
    for (int cf = 0; cf < 8; ++cf) { cs[cf] = 0.f; cq[cf] = 0.f; }
#pragma unroll
    for (int cf = 0; cf < 8; ++cf) {
#pragma unroll
      for (int r = 0; r < 4; ++r) {
        int row = wrow0 + rg * 4 + r;
        if (row < NNODES) {
          float v = fmaxf(acc[cf][r] + bl_[cf], 0.f);
          out[(size_t)row * NF + cf * 16 + col16] = v;
          cs[cf] += v;
          cq[cf] += v * v;
        }
      }
    }
#pragma unroll
    for (int cf = 0; cf < 8; ++cf) {
      cs[cf] += __shfl_xor(cs[cf], 16); cs[cf] += __shfl_xor(cs[cf], 32);
      cq[cf] += __shfl_xor(cq[cf], 16); cq[cf] += __shfl_xor(cq[cf], 32);
    }
    if (l < 16) {
#pragma unroll
      for (int cf = 0; cf < 8; ++cf) {
        red[0][wv][cf * 16 + l] = cs[cf];
        red[1][wv][cf * 16 + l] = cq[cf];
      }
    }
    __syncthreads();
    if (t < 128) {
      float s = red[0][0][t] + red[0][1][t] + red[0][2][t] + red[0][3][t];
      float q = red[1][0][t] + red[1][1][t] + red[1][2][t] + red[1][3][t];
      unsafeAtomicAdd(stats + t, s);
      unsafeAtomicAdd(stats + 128 + t, q);
    }
  } else {
#pragma unroll
    for (int cf = 0; cf < 8; ++cf) {
#pragma unroll
      for (int r = 0; r < 4; ++r) {
        int row = wrow0 + rg * 4 + r;
        if (row < NNODES)
          out[(size_t)row * NF + cf * 16 + col16] = acc[cf][r] + bl_[cf];
      }
    }
  }
}

// ---------------- K: BN scale/shift finalize ----------------
__global__ __launch_bounds__(128) void k_bnfin(const float* __restrict__ stats,
                                               const float* __restrict__ gamma,
                                               const float* __restrict__ beta,
                                               float* __restrict__ scsh) {
  int c = threadIdx.x;
  const float inv = 1.0f / (float)NNODES;
  float mean = stats[c] * inv;
  float var = stats[128 + c] * inv - mean * mean;
  var = fmaxf(var, 0.f);
  float sc = gamma[c] * rsqrtf(var + 1e-5f);
  scsh[c] = sc;
  scsh[128 + c] = beta[c] - mean * sc;
}

extern "C" void kernel_launch(void* const* d_in, const int* in_sizes, int n_in,
                              void* d_out, int out_size, void* d_ws, size_t ws_size,
                              hipStream_t stream) {
  const float* x     = (const float*)d_in[0];
  const int*   ei    = (const int*)d_in[1];
  const float* W1    = (const float*)d_in[2];
  const float* b1    = (const float*)d_in[3];
  const float* gamma = (const float*)d_in[4];
  const float* beta  = (const float*)d_in[5];
  const float* W2    = (const float*)d_in[6];
  const float* b2    = (const float*)d_in[7];
  float* out = (float*)d_out;
  float* h = (float*)d_out;   // h lives in d_out (rows rewritten in place per block)

  float*          stats = (float*)d_ws;                        // 512 floats
  unsigned short* wp    = (unsigned short*)(stats + 512);      // 65536 ushorts (128 KB)
  int*            deg   = (int*)(wp + 65536);                  // [NB*256]
  int*            off   = deg + NB * 256;                      // [NNODES+1]+pad
  int*            cursor= off + NNODES + 4;                    // [NNODES]
  int*            bsum  = cursor + NNODES;                     // [256]
  int*            boff  = bsum + 256;                          // [256]
  int*            slot  = boff + 256;                          // [NEDGES]

  k_wprep  <<<128, 256, 0, stream>>>(W1, W2, wp);
  k_zero   <<<NB, 256, 0, stream>>>(deg, stats);
  k_hist   <<<NEDGES / 256, 256, 0, stream>>>(ei, deg);
  k_scan1  <<<NB, 256, 0, stream>>>(deg, bsum);
  k_scan2  <<<1, 256, 0, stream>>>(bsum, boff);
  k_scan3  <<<NB, 256, 0, stream>>>(deg, boff, off, cursor);
  k_reorder<<<NEDGES / 256, 256, 0, stream>>>(ei, cursor, slot);
  k_gather <<<(NNODES + 3) / 4, 256, 0, stream>>>(x, off, slot, h);
  k_gemm<0><<<(NNODES + 63) / 64, 256, 0, stream>>>(h, wp, b1, nullptr, stats, h);
  k_bnfin  <<<1, 128, 0, stream>>>(stats, gamma, beta, stats + 256);
  k_gemm<1><<<(NNODES + 63) / 64, 256, 0, stream>>>(h, wp + 32768, b2, stats + 256, nullptr, out);
}